// Round 4
// baseline (900.089 us; speedup 1.0000x reference)
//
#include <hip/hip_runtime.h>

#define N 256
#define NLINE 4               // lines (waves) per block
#define NB (N / NLINE)        // 64 blocks
#define NT (NLINE * 64)       // 256 threads
#define LAM 0.05f             // step = ALPHA/2
#define MAXIT 35
#define TOL 0.01f

// broadcast-read one lane's register (lane index is wave-uniform -> v_readlane)
__device__ __forceinline__ float rlane(float v, int lane) {
    return __int_as_float(__builtin_amdgcn_readlane(__float_as_int(v), lane));
}

// 256-float line distributed over the wave: element k lives in lane (k>>2), reg (k&3)
// (this mapping makes row-phase global loads/stores a single coalesced dwordx4/lane)
struct Dist { float r0, r1, r2, r3; };

// branchless fetch: 4 independent readlanes + 2 uniform selects
__device__ __forceinline__ float dfetch(const Dist& d, int k) {
    const int lane = k >> 2;
    const int sel = k & 3;
    float a = rlane(d.r0, lane);
    float b = rlane(d.r1, lane);
    float c = rlane(d.r2, lane);
    float e = rlane(d.r3, lane);
    float ab = (sel & 1) ? b : a;
    float ce = (sel & 1) ? e : c;
    return (sel & 2) ? ce : ab;
}

// O(1) segment flush: o[j] = val for j in [lo, hi]; element j of reg r is 4*lane + r
__device__ __forceinline__ void flushseg(Dist& o, int lo, int hi, float val, int lane) {
    const unsigned len = (unsigned)(hi - lo);
    const int base = 4 * lane - lo;
    o.r0 = ((unsigned)(base    ) <= len) ? val : o.r0;
    o.r1 = ((unsigned)(base + 1) <= len) ? val : o.r1;
    o.r2 = ((unsigned)(base + 2) <= len) ? val : o.r2;
    o.r3 = ((unsigned)(base + 3) <= len) ? val : o.r3;
}

// Condat's exact 1D TV prox; wave-uniform control, register-resident line,
// 2-deep value pipeline (vn1, vn2) so the dominant jump path needs no refetch.
__device__ void tv1d_scan(const Dist& v, Dist& o, const int lane)
{
    const float lam = LAM, mlam = -LAM, twolam = 2.0f * LAM;
    int k = 0, k0 = 0, km = 0, kp = 0;
    float umin = lam, umax = mlam;
    const float v0 = rlane(v.r0, 0);
    float vmin = v0 - lam, vmax = v0 + lam;
    float flen = 1.0f;                  // = k - k0 + 1
    float vn1 = dfetch(v, 1);           // v[k+1]
    float vn2 = dfetch(v, 2);           // v[k+2] (clamped at boundary)
    int guard = 0;
    for (;;) {
        if (++guard > 4000) return;     // provably terminates; belt+suspenders
        if (k == N - 1) {
            for (;;) {                  // boundary resolution (state-only, no vn use)
                if (umin < 0.0f) {
                    flushseg(o, k0, km, vmin, lane);
                    k0 = km + 1;
                    if (k0 > N - 1) return;
                    km = k = k0;
                    vmin = dfetch(v, k0);
                    umin = lam;
                    umax = vmin + lam - vmax;
                    flen = 1.0f;
                } else if (umax > 0.0f) {
                    flushseg(o, k0, kp, vmax, lane);
                    k0 = kp + 1;
                    if (k0 > N - 1) return;
                    kp = k = k0;
                    vmax = dfetch(v, k0);
                    umax = mlam;
                    umin = vmax - lam - vmin;
                    flen = 1.0f;
                } else {
                    vmin += umin / flen;
                    flushseg(o, k0, k, vmin, lane);
                    return;
                }
                if (k != N - 1) break;
                if (++guard > 4000) return;
            }
            vn1 = dfetch(v, k + 1);
            vn2 = dfetch(v, (k + 2 <= N - 1) ? k + 2 : N - 1);
            continue;
        }
        // invariant: vn1 = v[k+1], vn2 = v[k+2] (clamped)
        const int kpre = (k + 3 <= N - 1) ? k + 3 : N - 1;
        const float vnn = dfetch(v, kpre);           // speculative v[k+3], off-chain
        const float un = umin + vn1 - vmin;
        const float ux = umax + vn1 - vmax;
        if (un < mlam) {                             // negative jump
            flushseg(o, k0, km, vmin, lane);
            const bool fresh = (km == k);            // common: segment died young
            k0 = km + 1;
            k = k0;
            if (fresh) {
                vmin = vn1;                          // v[k0] == old v[k+1]
                vn1 = vn2; vn2 = vnn;                // pipeline shifts, no refetch
            } else {
                vmin = dfetch(v, k0);
                vn1 = dfetch(v, (k0 + 1 <= N - 1) ? k0 + 1 : N - 1);
                vn2 = dfetch(v, (k0 + 2 <= N - 1) ? k0 + 2 : N - 1);
            }
            km = k0; kp = k0;
            vmax = vmin + twolam;
            umin = lam; umax = mlam;
            flen = 1.0f;
        } else if (ux > lam) {                       // positive jump
            flushseg(o, k0, kp, vmax, lane);
            const bool fresh = (kp == k);
            k0 = kp + 1;
            k = k0;
            if (fresh) {
                vmax = vn1;
                vn1 = vn2; vn2 = vnn;
            } else {
                vmax = dfetch(v, k0);
                vn1 = dfetch(v, (k0 + 1 <= N - 1) ? k0 + 1 : N - 1);
                vn2 = dfetch(v, (k0 + 2 <= N - 1) ? k0 + 2 : N - 1);
            }
            km = k0; kp = k0;
            vmin = vmax - twolam;
            umin = lam; umax = mlam;
            flen = 1.0f;
        } else {                                     // no jump (predicated updates)
            k++;
            flen += 1.0f;
            const float r = __builtin_amdgcn_rcpf(flen);
            const bool cmin = (un >= lam);
            const bool cmax = (ux <= mlam);
            vmin = cmin ? fmaf(un - lam, r, vmin) : vmin;
            km   = cmin ? k : km;
            umin = cmin ? lam : un;
            vmax = cmax ? fmaf(ux + lam, r, vmax) : vmax;
            kp   = cmax ? k : kp;
            umax = cmax ? mlam : ux;
            vn1 = vn2; vn2 = vnn;
        }
    }
}

// lean grid barrier: counter + generation, agent scope. Requires co-residency
// (guaranteed by cooperative launch) and cnt=gen=0 at kernel start (hipMemsetAsync).
__device__ __forceinline__ void gridbar(unsigned* cnt, unsigned* gen) {
    __syncthreads();
    if (threadIdx.x == 0) {
        __threadfence();                                         // release (agent)
        unsigned g = __hip_atomic_load(gen, __ATOMIC_RELAXED, __HIP_MEMORY_SCOPE_AGENT);
        unsigned a = __hip_atomic_fetch_add(cnt, 1u, __ATOMIC_RELAXED, __HIP_MEMORY_SCOPE_AGENT);
        if (a == NB - 1) {
            __hip_atomic_store(cnt, 0u, __ATOMIC_RELAXED, __HIP_MEMORY_SCOPE_AGENT);
            __hip_atomic_fetch_add(gen, 1u, __ATOMIC_RELEASE, __HIP_MEMORY_SCOPE_AGENT);
        } else {
            while (__hip_atomic_load(gen, __ATOMIC_RELAXED, __HIP_MEMORY_SCOPE_AGENT) == g)
                __builtin_amdgcn_s_sleep(1);
        }
        __threadfence();                                         // acquire (agent)
    }
    __syncthreads();
}

// Douglas-Rachford TV2D: wave w of block b owns column (4b+w) in phase 1 and row (4b+w)
// in phase 2. p (column-local) and q (row-local) persist in registers across iterations.
__global__ __launch_bounds__(NT) void tv2d_coop(const float* __restrict__ X,
                                                float* __restrict__ xw,   // = d_out
                                                float* __restrict__ y,
                                                unsigned* __restrict__ bar,  // [cnt, gen]
                                                unsigned* __restrict__ acc)  // [MAXIT]
{
    const int t = threadIdx.x;
    const int lane = t & 63;
    const int wave = t >> 6;
    const int line = blockIdx.x * NLINE + wave;

    Dist p = {0.f, 0.f, 0.f, 0.f};
    Dist q = {0.f, 0.f, 0.f, 0.f};

    for (int it = 0; it < MAXIT; ++it) {
        // ---- column phase: y = prox(x + p) on column `line`; p = v - y ----
        const float* xs = (it == 0) ? X : xw;
        const float* col = xs + line;
        Dist v, o;
        v.r0 = col[(4 * lane    ) * N] + p.r0;
        v.r1 = col[(4 * lane + 1) * N] + p.r1;
        v.r2 = col[(4 * lane + 2) * N] + p.r2;
        v.r3 = col[(4 * lane + 3) * N] + p.r3;
        tv1d_scan(v, o, lane);
        p.r0 = v.r0 - o.r0;  p.r1 = v.r1 - o.r1;
        p.r2 = v.r2 - o.r2;  p.r3 = v.r3 - o.r3;
        float* ycol = y + line;
        ycol[(4 * lane    ) * N] = o.r0;
        ycol[(4 * lane + 1) * N] = o.r1;
        ycol[(4 * lane + 2) * N] = o.r2;
        ycol[(4 * lane + 3) * N] = o.r3;
        gridbar(bar, bar + 1);

        // ---- row phase: x2 = prox(y + q) on row `line`; q = v - x2; acc = max|y-x2| ----
        Dist w, o2;
        const float4 yv = *(const float4*)(y + line * N + 4 * lane);
        w.r0 = yv.x + q.r0;
        w.r1 = yv.y + q.r1;
        w.r2 = yv.z + q.r2;
        w.r3 = yv.w + q.r3;
        tv1d_scan(w, o2, lane);
        float d0 = yv.x - o2.r0;    // y - x2
        float d1 = yv.y - o2.r1;
        float d2 = yv.z - o2.r2;
        float d3 = yv.w - o2.r3;
        q.r0 = w.r0 - o2.r0;  q.r1 = w.r1 - o2.r1;
        q.r2 = w.r2 - o2.r2;  q.r3 = w.r3 - o2.r3;
        float4 xv;
        xv.x = o2.r0; xv.y = o2.r1; xv.z = o2.r2; xv.w = o2.r3;
        *(float4*)(xw + line * N + 4 * lane) = xv;

        float am = fmaxf(fmaxf(fabsf(d0), fabsf(d1)), fmaxf(fabsf(d2), fabsf(d3)));
        #pragma unroll
        for (int off = 32; off > 0; off >>= 1)
            am = fmaxf(am, __shfl_xor(am, off));
        if (lane == 0) atomicMax(&acc[it], __float_as_uint(am));  // am>=0: uint order == float order
        gridbar(bar, bar + 1);

        unsigned a = __hip_atomic_load(&acc[it], __ATOMIC_RELAXED, __HIP_MEMORY_SCOPE_AGENT);
        if (__uint_as_float(a) < TOL) break;   // uniform across grid
    }
}

extern "C" void kernel_launch(void* const* d_in, const int* in_sizes, int n_in,
                              void* d_out, int out_size, void* d_ws, size_t ws_size,
                              hipStream_t stream) {
    const float* X = (const float*)d_in[0];
    float* xw = (float*)d_out;
    float* y = (float*)d_ws;
    unsigned* bar = (unsigned*)((char*)d_ws + (size_t)N * N * sizeof(float));
    unsigned* acc = bar + 2;
    // zero barrier state + per-iteration acc slots before the kernel (capture-legal)
    hipMemsetAsync((void*)bar, 0, (2 + MAXIT) * sizeof(unsigned), stream);
    void* args[] = { (void*)&X, (void*)&xw, (void*)&y, (void*)&bar, (void*)&acc };
    hipLaunchCooperativeKernel((void*)tv2d_coop, dim3(NB), dim3(NT), args, 0, stream);
}

// Round 5
// 730.959 us; speedup vs baseline: 1.2314x; 1.2314x over previous
//
#include <hip/hip_runtime.h>

#define N 256
#define NLINE 4               // lines (waves) per block
#define NB (N / NLINE)        // 64 blocks
#define NT (NLINE * 64)       // 256 threads
#define LAM 0.05f             // step = ALPHA/2
#define MAXIT 35
#define TOL 0.01f

// broadcast-read one lane's register (lane index is wave-uniform -> v_readlane)
__device__ __forceinline__ float rlane(float v, int lane) {
    return __int_as_float(__builtin_amdgcn_readlane(__float_as_int(v), lane));
}

// 256-float line distributed over the wave: element k lives in lane (k>>2), reg (k&3)
// (row-phase global loads/stores become one coalesced dwordx4 per lane)
struct Dist { float r0, r1, r2, r3; };

// branchless fetch: 4 independent readlanes + 2 uniform selects
__device__ __forceinline__ float dfetch(const Dist& d, int k) {
    const int lane = k >> 2;
    const int sel = k & 3;
    float a = rlane(d.r0, lane);
    float b = rlane(d.r1, lane);
    float c = rlane(d.r2, lane);
    float e = rlane(d.r3, lane);
    float ab = (sel & 1) ? b : a;
    float ce = (sel & 1) ? e : c;
    return (sel & 2) ? ce : ab;
}

// O(1) segment flush: o[j] = val for j in [lo, hi]; element j of reg r is 4*lane + r
__device__ __forceinline__ void flushseg(Dist& o, int lo, int hi, float val, int lane) {
    const unsigned len = (unsigned)(hi - lo);
    const int base = 4 * lane - lo;
    o.r0 = ((unsigned)(base    ) <= len) ? val : o.r0;
    o.r1 = ((unsigned)(base + 1) <= len) ? val : o.r1;
    o.r2 = ((unsigned)(base + 2) <= len) ? val : o.r2;
    o.r3 = ((unsigned)(base + 3) <= len) ? val : o.r3;
}

// Condat's exact 1D TV prox; wave-uniform control, register-resident line.
// Hot path restructured to ONE resolved branch per step (merged neg/pos jump,
// predicated interior, rare integer-cond rewind branch, 2x unrolled loop).
__device__ void tv1d_scan(const Dist& v, Dist& o, const int lane)
{
    const float lam = LAM, mlam = -LAM, twolam = 2.0f * LAM;
    int k = 0, k0 = 0, km = 0, kp = 0;
    float umin = lam, umax = mlam;
    const float v0 = rlane(v.r0, 0);
    float vmin = v0 - lam, vmax = v0 + lam;
    float flen = 1.0f;                  // = k - k0 + 1
    float vn1 = dfetch(v, 1);           // v[k+1]
    float vn2 = dfetch(v, 2);           // v[k+2] (clamped at boundary)
    int guard = 0;

    auto step = [&]() {
        const int kpre = (k + 3 <= N - 1) ? k + 3 : N - 1;
        const float vnn = dfetch(v, kpre);           // speculative v[k+3], off-chain
        const float un = umin + vn1 - vmin;
        const float ux = umax + vn1 - vmax;
        const bool neg = un < mlam;
        const bool pos = ux > lam;
        if (__builtin_expect((int)(neg | pos), 1)) {     // JUMP (dominant, one branch)
            const float fval = neg ? vmin : vmax;
            const int   fhi  = neg ? km : kp;
            flushseg(o, k0, fhi, fval, lane);
            k0 = fhi + 1;
            float vstar, w1, w2;
            if (__builtin_expect((int)(k0 <= k), 0)) {   // rewind (rare, int cond)
                vstar = dfetch(v, k0);
                w1 = dfetch(v, (k0 + 1 <= N - 1) ? k0 + 1 : N - 1);
                w2 = dfetch(v, (k0 + 2 <= N - 1) ? k0 + 2 : N - 1);
            } else {                                     // fresh: k0 == k+1, rename only
                vstar = vn1; w1 = vn2; w2 = vnn;
            }
            vn1 = w1; vn2 = w2;
            k = k0; km = k0; kp = k0;
            vmin = neg ? vstar : vstar - twolam;         // neg: vstar; pos: vstar-2lam
            vmax = vmin + twolam;
            umin = lam; umax = mlam;
            flen = 1.0f;
        } else {                                         // no jump (~6%, predicated)
            k++;
            flen += 1.0f;
            const float r = __builtin_amdgcn_rcpf(flen);
            const bool cmin = (un >= lam);
            const bool cmax = (ux <= mlam);
            vmin = cmin ? fmaf(un - lam, r, vmin) : vmin;
            km   = cmin ? k : km;
            umin = cmin ? lam : un;
            vmax = cmax ? fmaf(ux + lam, r, vmax) : vmax;
            kp   = cmax ? k : kp;
            umax = cmax ? mlam : ux;
            vn1 = vn2; vn2 = vnn;
        }
    };

    for (;;) {
        while (k < N - 1) {             // 2x unrolled: 1 taken backedge / 2 steps
            if (++guard > 2000) return; // provably terminates; belt+suspenders
            step();
            if (k >= N - 1) break;
            step();
        }
        // boundary resolution at k == N-1 (verbatim semantics from verified R2)
        for (;;) {
            if (++guard > 4000) return;
            if (umin < 0.0f) {                       // negative jump at right boundary
                flushseg(o, k0, km, vmin, lane);
                k0 = km + 1;
                if (k0 > N - 1) return;
                km = k = k0;
                vmin = dfetch(v, k0);
                umin = lam;
                umax = vmin + lam - vmax;
                flen = 1.0f;
            } else if (umax > 0.0f) {                // positive jump at right boundary
                flushseg(o, k0, kp, vmax, lane);
                k0 = kp + 1;
                if (k0 > N - 1) return;
                kp = k = k0;
                vmax = dfetch(v, k0);
                umax = mlam;
                umin = vmax - lam - vmin;
                flen = 1.0f;
            } else {                                 // done: flush last segment
                vmin += umin / flen;
                flushseg(o, k0, k, vmin, lane);
                return;
            }
            if (k != N - 1) break;                   // resume main loop
        }
        vn1 = dfetch(v, k + 1);                      // refill pipeline
        vn2 = dfetch(v, (k + 2 <= N - 1) ? k + 2 : N - 1);
    }
}

// lean grid barrier: counter + generation, agent scope. Requires co-residency
// (guaranteed by cooperative launch) and cnt=gen=0 at kernel start (hipMemsetAsync).
__device__ __forceinline__ void gridbar(unsigned* cnt, unsigned* gen) {
    __syncthreads();
    if (threadIdx.x == 0) {
        __threadfence();                                         // release (agent)
        unsigned g = __hip_atomic_load(gen, __ATOMIC_RELAXED, __HIP_MEMORY_SCOPE_AGENT);
        unsigned a = __hip_atomic_fetch_add(cnt, 1u, __ATOMIC_RELAXED, __HIP_MEMORY_SCOPE_AGENT);
        if (a == NB - 1) {
            __hip_atomic_store(cnt, 0u, __ATOMIC_RELAXED, __HIP_MEMORY_SCOPE_AGENT);
            __hip_atomic_fetch_add(gen, 1u, __ATOMIC_RELEASE, __HIP_MEMORY_SCOPE_AGENT);
        } else {
            while (__hip_atomic_load(gen, __ATOMIC_RELAXED, __HIP_MEMORY_SCOPE_AGENT) == g)
                __builtin_amdgcn_s_sleep(1);
        }
        __threadfence();                                         // acquire (agent)
    }
    __syncthreads();
}

// Douglas-Rachford TV2D: wave w of block b owns column (4b+w) in phase 1 and row (4b+w)
// in phase 2. p (column-local) and q (row-local) persist in registers across iterations.
__global__ __launch_bounds__(NT) void tv2d_coop(const float* __restrict__ X,
                                                float* __restrict__ xw,   // = d_out
                                                float* __restrict__ y,
                                                unsigned* __restrict__ bar,  // [cnt, gen]
                                                unsigned* __restrict__ acc)  // [MAXIT]
{
    const int t = threadIdx.x;
    const int lane = t & 63;
    const int wave = t >> 6;
    const int line = blockIdx.x * NLINE + wave;

    Dist p = {0.f, 0.f, 0.f, 0.f};
    Dist q = {0.f, 0.f, 0.f, 0.f};

    for (int it = 0; it < MAXIT; ++it) {
        // ---- column phase: y = prox(x + p) on column `line`; p = v - y ----
        const float* xs = (it == 0) ? X : xw;
        const float* col = xs + line;
        Dist v, o;
        v.r0 = col[(4 * lane    ) * N] + p.r0;
        v.r1 = col[(4 * lane + 1) * N] + p.r1;
        v.r2 = col[(4 * lane + 2) * N] + p.r2;
        v.r3 = col[(4 * lane + 3) * N] + p.r3;
        tv1d_scan(v, o, lane);
        p.r0 = v.r0 - o.r0;  p.r1 = v.r1 - o.r1;
        p.r2 = v.r2 - o.r2;  p.r3 = v.r3 - o.r3;
        float* ycol = y + line;
        ycol[(4 * lane    ) * N] = o.r0;
        ycol[(4 * lane + 1) * N] = o.r1;
        ycol[(4 * lane + 2) * N] = o.r2;
        ycol[(4 * lane + 3) * N] = o.r3;
        gridbar(bar, bar + 1);

        // ---- row phase: x2 = prox(y + q) on row `line`; q = v - x2; acc = max|y-x2| ----
        Dist w, o2;
        const float4 yv = *(const float4*)(y + line * N + 4 * lane);
        w.r0 = yv.x + q.r0;
        w.r1 = yv.y + q.r1;
        w.r2 = yv.z + q.r2;
        w.r3 = yv.w + q.r3;
        tv1d_scan(w, o2, lane);
        float d0 = yv.x - o2.r0;    // y - x2
        float d1 = yv.y - o2.r1;
        float d2 = yv.z - o2.r2;
        float d3 = yv.w - o2.r3;
        q.r0 = w.r0 - o2.r0;  q.r1 = w.r1 - o2.r1;
        q.r2 = w.r2 - o2.r2;  q.r3 = w.r3 - o2.r3;
        float4 xv;
        xv.x = o2.r0; xv.y = o2.r1; xv.z = o2.r2; xv.w = o2.r3;
        *(float4*)(xw + line * N + 4 * lane) = xv;

        float am = fmaxf(fmaxf(fabsf(d0), fabsf(d1)), fmaxf(fabsf(d2), fabsf(d3)));
        #pragma unroll
        for (int off = 32; off > 0; off >>= 1)
            am = fmaxf(am, __shfl_xor(am, off));
        if (lane == 0) atomicMax(&acc[it], __float_as_uint(am));  // am>=0: uint order == float order
        gridbar(bar, bar + 1);

        unsigned a = __hip_atomic_load(&acc[it], __ATOMIC_RELAXED, __HIP_MEMORY_SCOPE_AGENT);
        if (__uint_as_float(a) < TOL) break;   // uniform across grid
    }
}

extern "C" void kernel_launch(void* const* d_in, const int* in_sizes, int n_in,
                              void* d_out, int out_size, void* d_ws, size_t ws_size,
                              hipStream_t stream) {
    const float* X = (const float*)d_in[0];
    float* xw = (float*)d_out;
    float* y = (float*)d_ws;
    unsigned* bar = (unsigned*)((char*)d_ws + (size_t)N * N * sizeof(float));
    unsigned* acc = bar + 2;
    // zero barrier state + per-iteration acc slots before the kernel (capture-legal)
    hipMemsetAsync((void*)bar, 0, (2 + MAXIT) * sizeof(unsigned), stream);
    void* args[] = { (void*)&X, (void*)&xw, (void*)&y, (void*)&bar, (void*)&acc };
    hipLaunchCooperativeKernel((void*)tv2d_coop, dim3(NB), dim3(NT), args, 0, stream);
}

// Round 6
// 428.000 us; speedup vs baseline: 2.1030x; 1.7078x over previous
//
#include <hip/hip_runtime.h>

#define N 256
#define NLINE 4               // lines (waves) per block
#define NB (N / NLINE)        // 64 blocks
#define NT (NLINE * 64)       // 256 threads
#define LAM 0.05f             // step = ALPHA/2
#define FOURLAM (4.0f * LAM)
#define MAXIT 35
#define TOL 0.01f

// broadcast-read one lane's register (lane index is wave-uniform -> v_readlane)
__device__ __forceinline__ float rlane(float v, int lane) {
    return __int_as_float(__builtin_amdgcn_readlane(__float_as_int(v), lane));
}

// 256-float line distributed over the wave: element k lives in lane (k>>2), reg (k&3)
// (row-phase global loads/stores become one coalesced dwordx4 per lane)
struct Dist { float r0, r1, r2, r3; };

// branchless fetch: 4 independent readlanes + 2 uniform selects
__device__ __forceinline__ float dfetch(const Dist& d, int k) {
    const int lane = k >> 2;
    const int sel = k & 3;
    float a = rlane(d.r0, lane);
    float b = rlane(d.r1, lane);
    float c = rlane(d.r2, lane);
    float e = rlane(d.r3, lane);
    float ab = (sel & 1) ? b : a;
    float ce = (sel & 1) ? e : c;
    return (sel & 2) ? ce : ab;
}

// O(1) segment flush: o[j] = val for j in [lo, hi]
__device__ __forceinline__ void flushseg(Dist& o, int lo, int hi, float val, int lane) {
    const unsigned len = (unsigned)(hi - lo);
    const int base = 4 * lane - lo;
    o.r0 = ((unsigned)(base    ) <= len) ? val : o.r0;
    o.r1 = ((unsigned)(base + 1) <= len) ? val : o.r1;
    o.r2 = ((unsigned)(base + 2) <= len) ? val : o.r2;
    o.r3 = ((unsigned)(base + 3) <= len) ? val : o.r3;
}

// scalar 4-way select of a 64-bit mask (s_cselect_b64, no memory)
__device__ __forceinline__ unsigned long long sel4(unsigned long long a, unsigned long long b,
                                                   unsigned long long c, unsigned long long d, int r) {
    unsigned long long ab = (r & 1) ? b : a;
    unsigned long long cd = (r & 1) ? d : c;
    return (r & 2) ? cd : ab;
}

// Condat's exact 1D TV prox; wave-uniform control, register-resident line.
// Serial hot path (R5) + lane-parallel fast-forward over runs of guaranteed jumps:
// from any fresh state, |v[j+1]-v[j]| > 4*lam forces a jump with dir = sign(d[j]),
// output o[j] = v[j] + lam*(s_j - s_{j-1}); runs are emitted in O(1).
__device__ void tv1d_scan(const Dist& v, Dist& o, const int lane)
{
    const float lam = LAM, mlam = -LAM, twolam = 2.0f * LAM;

    // ---- per-scan precompute for fast-forward (vectorized, ~once) ----
    Dist vnx;                                    // vnx[j] = v[j+1] (j=255 garbage)
    vnx.r0 = v.r1; vnx.r1 = v.r2; vnx.r2 = v.r3;
    vnx.r3 = __shfl_down(v.r0, 1);
    Dist d;
    d.r0 = vnx.r0 - v.r0;  d.r1 = vnx.r1 - v.r1;
    d.r2 = vnx.r2 - v.r2;  d.r3 = vnx.r3 - v.r3;
    const unsigned lambits = __float_as_uint(lam);
    Dist sl;                                     // sl[j] = sign(d[j]) * lam
    sl.r0 = __uint_as_float((__float_as_uint(d.r0) & 0x80000000u) | lambits);
    sl.r1 = __uint_as_float((__float_as_uint(d.r1) & 0x80000000u) | lambits);
    sl.r2 = __uint_as_float((__float_as_uint(d.r2) & 0x80000000u) | lambits);
    sl.r3 = __uint_as_float((__float_as_uint(d.r3) & 0x80000000u) | lambits);
    Dist slp;                                    // slp[j] = sl[j-1], slp[0] = 0
    slp.r1 = sl.r0; slp.r2 = sl.r1; slp.r3 = sl.r2;
    {
        float s3u = __shfl_up(sl.r3, 1);
        slp.r0 = (lane == 0) ? 0.0f : s3u;
    }
    Dist e;                                      // e[j] = v[j] + sl[j] - slp[j]
    e.r0 = v.r0 + sl.r0 - slp.r0;
    e.r1 = v.r1 + sl.r1 - slp.r1;
    e.r2 = v.r2 + sl.r2 - slp.r2;
    e.r3 = v.r3 + sl.r3 - slp.r3;
    unsigned long long B0 = __ballot(fabsf(d.r0) > FOURLAM);
    unsigned long long B1 = __ballot(fabsf(d.r1) > FOURLAM);
    unsigned long long B2 = __ballot(fabsf(d.r2) > FOURLAM);
    unsigned long long B3 = __ballot(fabsf(d.r3) > FOURLAM) & 0x7FFFFFFFFFFFFFFFull; // j=255 invalid
    unsigned long long S0 = __ballot(d.r0 < 0.0f);
    unsigned long long S1 = __ballot(d.r1 < 0.0f);
    unsigned long long S2 = __ballot(d.r2 < 0.0f);
    unsigned long long S3 = __ballot(d.r3 < 0.0f);

    // ---- serial state ----
    int k = 0, k0 = 0, km = 0, kp = 0;
    float umin = lam, umax = mlam;
    const float v0 = rlane(v.r0, 0);
    float vmin = v0 - lam, vmax = v0 + lam;
    float flen = 1.0f;                  // = k - k0 + 1
    float vn1 = dfetch(v, 1);           // v[k+1]
    float vn2 = dfetch(v, 2);           // v[k+2] (clamped at boundary)
    int guard = 0;

    auto bigbit = [&](int j) -> int {
        return (int)((sel4(B0, B1, B2, B3, j & 3) >> (j >> 2)) & 1ull);
    };

    // pre: fresh state at k (= k0 = km = kp), bigbit(k) true, k <= N-2
    auto fastfwd = [&]() {
        // K1 = first j >= k with !big[j]  (exists: bit for j=255 is 0)
        int K1 = 256;
        {
            int Lmin0 = (k + 3) >> 2;
            unsigned long long m0 = ~B0 & ((Lmin0 >= 64) ? 0ull : (~0ull << Lmin0));
            if (m0) { int el = 4 * (int)__builtin_ctzll(m0); K1 = (el < K1) ? el : K1; }
            int Lmin1 = (k + 2) >> 2;
            unsigned long long m1 = ~B1 & ((Lmin1 >= 64) ? 0ull : (~0ull << Lmin1));
            if (m1) { int el = 4 * (int)__builtin_ctzll(m1) + 1; K1 = (el < K1) ? el : K1; }
            int Lmin2 = (k + 1) >> 2;
            unsigned long long m2 = ~B2 & ((Lmin2 >= 64) ? 0ull : (~0ull << Lmin2));
            if (m2) { int el = 4 * (int)__builtin_ctzll(m2) + 2; K1 = (el < K1) ? el : K1; }
            int Lmin3 = k >> 2;
            unsigned long long m3 = ~B3 & ((Lmin3 >= 64) ? 0ull : (~0ull << Lmin3));
            if (m3) { int el = 4 * (int)__builtin_ctzll(m3) + 3; K1 = (el < K1) ? el : K1; }
        }
        // first run element: uses serial state's vmin/vmax (correct for ANY fresh sP)
        const int sneg = (int)((sel4(S0, S1, S2, S3, k & 3) >> (k >> 2)) & 1ull);
        const float fval0 = sneg ? vmin : vmax;
        flushseg(o, k, k, fval0, lane);
        if (K1 > k + 1) {               // elements (k, K1-1]: closed-form e[j]
            const int lo = k + 1;
            const unsigned len = (unsigned)(K1 - 1 - lo);
            const int base = 4 * lane - lo;
            o.r0 = ((unsigned)(base    ) <= len) ? e.r0 : o.r0;
            o.r1 = ((unsigned)(base + 1) <= len) ? e.r1 : o.r1;
            o.r2 = ((unsigned)(base + 2) <= len) ? e.r2 : o.r2;
            o.r3 = ((unsigned)(base + 3) <= len) ? e.r3 : o.r3;
        }
        // exit state: fresh at K1, sP = sign(d[K1-1]);  vmin = v[K1] - lam - sl[K1-1]
        k = K1; k0 = K1; km = K1; kp = K1;
        const float vK = dfetch(v, K1);
        const float sp = dfetch(slp, K1);       // = sl[K1-1]
        vmin = vK - lam - sp;
        vmax = vmin + twolam;
        umin = lam; umax = mlam;
        flen = 1.0f;
        if (K1 < N - 1) {
            vn1 = dfetch(v, K1 + 1);
            vn2 = dfetch(v, (K1 + 2 <= N - 1) ? K1 + 2 : N - 1);
        }
    };

    auto step = [&]() {
        const int kpre = (k + 3 <= N - 1) ? k + 3 : N - 1;
        const float vnn = dfetch(v, kpre);           // speculative v[k+3], off-chain
        const float un = umin + vn1 - vmin;
        const float ux = umax + vn1 - vmax;
        const bool neg = un < mlam;
        const bool pos = ux > lam;
        if (__builtin_expect((int)(neg | pos), 1)) {     // JUMP
            const float fval = neg ? vmin : vmax;
            const int   fhi  = neg ? km : kp;
            flushseg(o, k0, fhi, fval, lane);
            k0 = fhi + 1;
            float vstar, w1, w2;
            if (__builtin_expect((int)(k0 <= k), 0)) {   // rewind (rare)
                vstar = dfetch(v, k0);
                w1 = dfetch(v, (k0 + 1 <= N - 1) ? k0 + 1 : N - 1);
                w2 = dfetch(v, (k0 + 2 <= N - 1) ? k0 + 2 : N - 1);
            } else {                                     // fresh: rename only
                vstar = vn1; w1 = vn2; w2 = vnn;
            }
            vn1 = w1; vn2 = w2;
            k = k0; km = k0; kp = k0;
            vmin = neg ? vstar : vstar - twolam;
            vmax = vmin + twolam;
            umin = lam; umax = mlam;
            flen = 1.0f;
            if (bigbit(k)) fastfwd();                    // run of guaranteed jumps
        } else {                                         // no jump (predicated)
            k++;
            flen += 1.0f;
            const float r = __builtin_amdgcn_rcpf(flen);
            const bool cmin = (un >= lam);
            const bool cmax = (ux <= mlam);
            vmin = cmin ? fmaf(un - lam, r, vmin) : vmin;
            km   = cmin ? k : km;
            umin = cmin ? lam : un;
            vmax = cmax ? fmaf(ux + lam, r, vmax) : vmax;
            kp   = cmax ? k : kp;
            umax = cmax ? mlam : ux;
            vn1 = vn2; vn2 = vnn;
        }
    };

    // init state is fresh-like with windows ±3lam (< 4lam) and sP = 0 -> FF valid
    if (bigbit(0)) fastfwd();

    for (;;) {
        while (k < N - 1) {
            if (++guard > 2000) return; // provably terminates; belt+suspenders
            step();
            if (k >= N - 1) break;
            step();
        }
        // boundary resolution at k == N-1 (verbatim semantics from verified R2)
        for (;;) {
            if (++guard > 4000) return;
            if (umin < 0.0f) {                       // negative jump at right boundary
                flushseg(o, k0, km, vmin, lane);
                k0 = km + 1;
                if (k0 > N - 1) return;
                km = k = k0;
                vmin = dfetch(v, k0);
                umin = lam;
                umax = vmin + lam - vmax;
                flen = 1.0f;
            } else if (umax > 0.0f) {                // positive jump at right boundary
                flushseg(o, k0, kp, vmax, lane);
                k0 = kp + 1;
                if (k0 > N - 1) return;
                kp = k = k0;
                vmax = dfetch(v, k0);
                umax = mlam;
                umin = vmax - lam - vmin;
                flen = 1.0f;
            } else {                                 // done: flush last segment
                vmin += umin / flen;
                flushseg(o, k0, k, vmin, lane);
                return;
            }
            if (k != N - 1) break;                   // resume main loop
        }
        vn1 = dfetch(v, k + 1);                      // refill pipeline
        vn2 = dfetch(v, (k + 2 <= N - 1) ? k + 2 : N - 1);
    }
}

// lean grid barrier: counter + generation, agent scope. Requires co-residency
// (guaranteed by cooperative launch) and cnt=gen=0 at kernel start (hipMemsetAsync).
__device__ __forceinline__ void gridbar(unsigned* cnt, unsigned* gen) {
    __syncthreads();
    if (threadIdx.x == 0) {
        __threadfence();                                         // release (agent)
        unsigned g = __hip_atomic_load(gen, __ATOMIC_RELAXED, __HIP_MEMORY_SCOPE_AGENT);
        unsigned a = __hip_atomic_fetch_add(cnt, 1u, __ATOMIC_RELAXED, __HIP_MEMORY_SCOPE_AGENT);
        if (a == NB - 1) {
            __hip_atomic_store(cnt, 0u, __ATOMIC_RELAXED, __HIP_MEMORY_SCOPE_AGENT);
            __hip_atomic_fetch_add(gen, 1u, __ATOMIC_RELEASE, __HIP_MEMORY_SCOPE_AGENT);
        } else {
            while (__hip_atomic_load(gen, __ATOMIC_RELAXED, __HIP_MEMORY_SCOPE_AGENT) == g)
                __builtin_amdgcn_s_sleep(1);
        }
        __threadfence();                                         // acquire (agent)
    }
    __syncthreads();
}

// Douglas-Rachford TV2D: wave w of block b owns column (4b+w) in phase 1 and row (4b+w)
// in phase 2. p (column-local) and q (row-local) persist in registers across iterations.
__global__ __launch_bounds__(NT) void tv2d_coop(const float* __restrict__ X,
                                                float* __restrict__ xw,   // = d_out
                                                float* __restrict__ y,
                                                unsigned* __restrict__ bar,  // [cnt, gen]
                                                unsigned* __restrict__ acc)  // [MAXIT]
{
    const int t = threadIdx.x;
    const int lane = t & 63;
    const int wave = t >> 6;
    const int line = blockIdx.x * NLINE + wave;

    Dist p = {0.f, 0.f, 0.f, 0.f};
    Dist q = {0.f, 0.f, 0.f, 0.f};

    for (int it = 0; it < MAXIT; ++it) {
        // ---- column phase: y = prox(x + p) on column `line`; p = v - y ----
        const float* xs = (it == 0) ? X : xw;
        const float* col = xs + line;
        Dist v, o;
        v.r0 = col[(4 * lane    ) * N] + p.r0;
        v.r1 = col[(4 * lane + 1) * N] + p.r1;
        v.r2 = col[(4 * lane + 2) * N] + p.r2;
        v.r3 = col[(4 * lane + 3) * N] + p.r3;
        tv1d_scan(v, o, lane);
        p.r0 = v.r0 - o.r0;  p.r1 = v.r1 - o.r1;
        p.r2 = v.r2 - o.r2;  p.r3 = v.r3 - o.r3;
        float* ycol = y + line;
        ycol[(4 * lane    ) * N] = o.r0;
        ycol[(4 * lane + 1) * N] = o.r1;
        ycol[(4 * lane + 2) * N] = o.r2;
        ycol[(4 * lane + 3) * N] = o.r3;
        gridbar(bar, bar + 1);

        // ---- row phase: x2 = prox(y + q) on row `line`; q = v - x2; acc = max|y-x2| ----
        Dist w, o2;
        const float4 yv = *(const float4*)(y + line * N + 4 * lane);
        w.r0 = yv.x + q.r0;
        w.r1 = yv.y + q.r1;
        w.r2 = yv.z + q.r2;
        w.r3 = yv.w + q.r3;
        tv1d_scan(w, o2, lane);
        float d0 = yv.x - o2.r0;    // y - x2
        float d1 = yv.y - o2.r1;
        float d2 = yv.z - o2.r2;
        float d3 = yv.w - o2.r3;
        q.r0 = w.r0 - o2.r0;  q.r1 = w.r1 - o2.r1;
        q.r2 = w.r2 - o2.r2;  q.r3 = w.r3 - o2.r3;
        float4 xv;
        xv.x = o2.r0; xv.y = o2.r1; xv.z = o2.r2; xv.w = o2.r3;
        *(float4*)(xw + line * N + 4 * lane) = xv;

        float am = fmaxf(fmaxf(fabsf(d0), fabsf(d1)), fmaxf(fabsf(d2), fabsf(d3)));
        #pragma unroll
        for (int off = 32; off > 0; off >>= 1)
            am = fmaxf(am, __shfl_xor(am, off));
        if (lane == 0) atomicMax(&acc[it], __float_as_uint(am));  // am>=0: uint order == float order
        gridbar(bar, bar + 1);

        unsigned a = __hip_atomic_load(&acc[it], __ATOMIC_RELAXED, __HIP_MEMORY_SCOPE_AGENT);
        if (__uint_as_float(a) < TOL) break;   // uniform across grid
    }
}

extern "C" void kernel_launch(void* const* d_in, const int* in_sizes, int n_in,
                              void* d_out, int out_size, void* d_ws, size_t ws_size,
                              hipStream_t stream) {
    const float* X = (const float*)d_in[0];
    float* xw = (float*)d_out;
    float* y = (float*)d_ws;
    unsigned* bar = (unsigned*)((char*)d_ws + (size_t)N * N * sizeof(float));
    unsigned* acc = bar + 2;
    // zero barrier state + per-iteration acc slots before the kernel (capture-legal)
    hipMemsetAsync((void*)bar, 0, (2 + MAXIT) * sizeof(unsigned), stream);
    void* args[] = { (void*)&X, (void*)&xw, (void*)&y, (void*)&bar, (void*)&acc };
    hipLaunchCooperativeKernel((void*)tv2d_coop, dim3(NB), dim3(NT), args, 0, stream);
}